// Round 1
// baseline (124.074 us; speedup 1.0000x reference)
//
#include <hip/hip_runtime.h>

// NormalizingFlow: 4 layers of monotonic linear-rational splines (pyro-style),
// B=262144 rows, D=64 dims, K=8 bins.
//
// Approach: each spline sub-piece (bin x lambda-half) is a Mobius map
// f(x)=(Ax+B)/(Cx+D); Mobius maps compose, so the full 4-layer chain per
// dimension is piecewise-Mobius with <= 61 pieces. Precompute (on device,
// fp64) per-(d,piece) coefficients + boundaries; main kernel is a single
// memory-bound pass: search piece, evaluate Mobius, log-det from
// ln(det) - 2 ln|den|, wave-reduce log_det (wave 64 == D).

#define BATCH 262144
#define DIM   64
#define NLAY  4
#define NK    8

// double-region offsets in d_ws (units: doubles)
#define OFF_LB 0        // [4][64][17] layer input-space piece boundaries (EPS-embedded)
#define OFF_LY 4352     // [4][64][17] layer output-space piece boundaries
#define OFF_LM 8704     // [4][64][16][4] layer piece Mobius matrices (A,B,C,D)
#define OFF_LD 25088    // [4][64][16] log2(det) per layer piece
#define OFF_FB 29184    // [64][65] final composed boundaries (fp64 geometry)
// float-region offsets in d_ws (units: floats from base)
#define OFF_KN0 66688   // [8][64][4] fine knots bnd[8c+0..3] (bnd[0]=-inf dummy)
#define OFF_KN1 68736   // [8][64][4] fine knots bnd[8c+4..7]
#define OFF_CRS 70784   // [7][64] coarse knots bnd[8],bnd[16],...,bnd[56]
#define OFF_CF0 71232   // [64][64][4] piece coeffs (A,B,C,D) recentered+normalized
#define OFF_CF1 87616   // [64][64][2] piece (log2det, xmid)

__device__ __forceinline__ void softmax_knots(const float* p, float minb,
                                              float* kn, float* len) {
  float v[NK];
  float m = p[0];
  for (int k = 1; k < NK; ++k) m = fmaxf(m, p[k]);
  float s = 0.f;
  for (int k = 0; k < NK; ++k) { v[k] = expf(p[k] - m); s += v[k]; }
  float invs = 1.f / s;
  for (int k = 0; k < NK; ++k) v[k] = minb + (1.f - minb * (float)NK) * (v[k] * invs);
  kn[0] = -3.f;
  float c = 0.f;
  for (int k = 0; k < NK; ++k) { c += v[k]; kn[k+1] = 6.f * c - 3.f; }
  kn[NK] = 3.f;
  for (int k = 0; k < NK; ++k) len[k] = kn[k+1] - kn[k];
}

// P1: 256 threads = (layer l, dim d). Replicate reference fp32 param math,
// emit per-layer piece boundaries + Mobius matrices (fp64).
__global__ void nf_pre1(const float* __restrict__ uw, const float* __restrict__ uh,
                        const float* __restrict__ ud, const float* __restrict__ ul,
                        double* __restrict__ W) {
  int t = threadIdx.x;
  int l = t >> 6, d = t & 63;
  const float* pw  = uw + (l*DIM + d)*NK;
  const float* ph  = uh + (l*DIM + d)*NK;
  const float* pdv = ud + (l*DIM + d)*(NK-1);
  const float* pl  = ul + (l*DIM + d)*NK;

  float kw[NK+1], ww[NK], kh[NK+1], hh[NK], dv[NK+1], lm[NK];
  softmax_knots(pw, 1e-3f, kw, ww);
  softmax_knots(ph, 1e-3f, kh, hh);
  dv[0] = 1.f; dv[NK] = 1.f;
  for (int k = 0; k < NK-1; ++k) {
    float u = pdv[k];
    // jax.nn.softplus = max(x,0) + log1p(exp(-|x|)); then + MIN_D
    dv[k+1] = 1e-3f + (fmaxf(u, 0.f) + log1pf(expf(-fabsf(u))));
  }
  for (int k = 0; k < NK; ++k) {
    float sg = 1.f / (1.f + expf(-pl[k]));
    lm[k] = 0.95f * sg + 0.025f;          // (1-2*MIN_LAM)*sig + MIN_LAM
  }

  double* Lb = W + OFF_LB + (l*DIM + d)*17;
  double* Ly = W + OFF_LY + (l*DIM + d)*17;
  double* LM = W + OFF_LM + (l*DIM + d)*64;
  double* Ld = W + OFF_LD + (l*DIM + d)*16;
  Lb[0] = -3.0; Lb[16] = 3.0;
  Ly[0] = -3.0; Ly[16] = 3.0;
  for (int k = 0; k < NK; ++k) {
    float delta = hh[k] / ww[k];
    float wbf = sqrtf(dv[k] / dv[k+1]);
    float wcf = (lm[k]*dv[k] + (1.f-lm[k])*wbf*dv[k+1]) / delta;
    float yaf = kh[k], ybf = hh[k] + kh[k];
    float ycf = ((1.f-lm[k])*yaf + lm[k]*wbf*ybf) / ((1.f-lm[k]) + lm[k]*wbf);
    if (k) Lb[2*k] = (double)(kw[k] + 1.0e-6f);   // bin decision boundary (fp32 +EPS, as reference)
    Lb[2*k+1] = (double)kw[k] + (double)lm[k]*(double)ww[k];  // theta==lambda split
    Ly[2*k]   = (double)yaf;
    Ly[2*k+1] = (double)ycf;

    double icw = (double)kw[k], iw = (double)ww[k], il = (double)lm[k];
    double wb = wbf, wc = wcf, ya = yaf, yb = ybf, yc = ycf;
    // lower half: num = ya*il + th*(wc*yc - ya); den = il + th*(wc-1); th=(x-icw)/iw
    double n0 = ya*il, n1 = wc*yc - ya, d0 = il, d1 = wc - 1.0;
    double A = n1, Bv = n0*iw - n1*icw, C = d1, Dv = d0*iw - d1*icw;
    double* Mp = LM + (2*k)*4;
    Mp[0]=A; Mp[1]=Bv; Mp[2]=C; Mp[3]=Dv;
    Ld[2*k] = log2(A*Dv - Bv*C);
    // upper half
    n0 = wc*yc - il*wb*yb; n1 = wb*yb - wc*yc; d0 = wc - il*wb; d1 = wb - wc;
    A = n1; Bv = n0*iw - n1*icw; C = d1; Dv = d0*iw - d1*icw;
    Mp = LM + (2*k+1)*4;
    Mp[0]=A; Mp[1]=Bv; Mp[2]=C; Mp[3]=Dv;
    Ld[2*k+1] = log2(A*Dv - Bv*C);
  }
}

// P2: 64 blocks (d) x 64 threads. Pull every layer boundary back to x-space,
// sort by rank, emit fp64 geometry (Fb) + fp32 search tables (kn/crs).
__global__ void nf_pre2(double* __restrict__ W, float* __restrict__ F) {
  int d = blockIdx.x;
  int t = threadIdx.x;
  __shared__ double sx[64];
  if (t < 60) {
    int lp  = t / 15;        // owning layer
    int mth = t % 15 + 1;    // interior boundary index 1..15
    double x = W[OFF_LB + (lp*DIM + d)*17 + mth];
    for (int q = lp - 1; q >= 0; --q) {   // invert through earlier layers
      const double* Ly = W + OFF_LY + (q*DIM + d)*17;
      int j = 0;
      for (int k = 1; k <= 15; ++k) j += (x >= Ly[k]) ? 1 : 0;
      const double* M = W + OFF_LM + (q*DIM + d)*64 + j*4;
      x = (M[3]*x - M[1]) / (M[0] - M[2]*x);  // Mobius inverse
    }
    sx[t] = x;
  }
  __syncthreads();
  double* Fb = W + OFF_FB + d*65;
  if (t < 60) {
    double x = sx[t];
    int r = 0;
    for (int s2 = 0; s2 < 60; ++s2) {
      double o = sx[s2];
      r += (o < x || (o == x && s2 < t)) ? 1 : 0;
    }
    Fb[r+1] = x;
  }
  if (t == 0)  Fb[0] = -3.0;
  if (t >= 60) Fb[t+1] = 3.0;   // Fb[61..64] geometry pads
  __threadfence_block();
  __syncthreads();
  int j = t;
  float bf;
  if (j == 0)       bf = -1e30f;        // dummy slot (never compared)
  else if (j <= 60) bf = (float)Fb[j];
  else              bf = 1e30f;         // search pads: never counted
  int cw = j >> 3, r8 = j & 7;
  if (r8 < 4) F[OFF_KN0 + (cw*DIM + d)*4 + r8]     = bf;
  else        F[OFF_KN1 + (cw*DIM + d)*4 + (r8-4)] = bf;
  if (j >= 8 && (j & 7) == 0 && j <= 56) F[OFF_CRS + (j/8 - 1)*DIM + d] = bf;
}

// P3: 64 blocks (d) x 64 threads (piece p). Compose the 4 layer matrices along
// the chain at the piece midpoint; recenter + normalize; store fp32 coeffs.
__global__ void nf_pre3(const double* __restrict__ W, float* __restrict__ F) {
  int d = blockIdx.x;
  int p = threadIdx.x;
  const double* Fb = W + OFF_FB + d*65;
  double bl = Fb[p], br = Fb[p+1];
  float xmf = (float)(0.5*(bl+br));
  xmf = fminf(fmaxf(xmf, -3.f), 3.f);
  double xm = (double)xmf;
  double y = xm;
  double A=1.0, Bv=0.0, C=0.0, Dv=1.0, ld2 = 0.0;
  for (int q = 0; q < NLAY; ++q) {
    const double* Lb = W + OFF_LB + (q*DIM + d)*17;
    int j = 0;
    for (int k = 1; k <= 15; ++k) j += (y >= Lb[k]) ? 1 : 0;
    const double* M = W + OFF_LM + (q*DIM + d)*64 + j*4;
    ld2 += W[OFF_LD + (q*DIM + d)*16 + j];
    double A2 = M[0]*A + M[1]*C, B2 = M[0]*Bv + M[1]*Dv;
    double C2 = M[2]*A + M[3]*C, D2 = M[2]*Bv + M[3]*Dv;
    y = (M[0]*y + M[1]) / (M[2]*y + M[3]);
    A=A2; Bv=B2; C=C2; Dv=D2;
  }
  double Bp = A*xm + Bv, Dp = C*xm + Dv;   // recenter at xmid (conditioning)
  double s = fmax(fmax(fabs(A), fabs(Bp)), fmax(fabs(C), fabs(Dp)));
  if (!(s > 0.0)) s = 1.0;
  double inv = 1.0 / s;
  float4 c4;
  c4.x = (float)(A*inv); c4.y = (float)(Bp*inv);
  c4.z = (float)(C*inv); c4.w = (float)(Dp*inv);
  *(float4*)(F + OFF_CF0 + (size_t)(p*DIM + d)*4) = c4;
  float2 c2;
  c2.x = (float)(ld2 - 2.0*log2(s));  // log2(det) of stored matrix
  c2.y = xmf;
  *(float2*)(F + OFF_CF1 + (size_t)(p*DIM + d)*2) = c2;
}

// Main: one wave (64 lanes) per row; lane = dim. Two-level piece search
// (7 coarse knots in regs, fine knots via 2x ds_read_b128 from LDS,
// conflict-free [c][d][4] layout), coeffs from L2-resident ws tables.
__global__ __launch_bounds__(256) void nf_main(const float* __restrict__ X,
                                               const float* __restrict__ F,
                                               float* __restrict__ OUT,
                                               float* __restrict__ LDo) {
  __shared__ float skn[4096];   // kn0[2048] ++ kn1[2048], 16 KB
  int t = threadIdx.x;
  {
    const float4* src = (const float4*)(F + OFF_KN0);
    float4* dst = (float4*)skn;
    for (int i = t; i < 1024; i += 256) dst[i] = src[i];
  }
  int d = t & 63;
  float k1 = F[OFF_CRS + 0*DIM + d];
  float k2 = F[OFF_CRS + 1*DIM + d];
  float k3 = F[OFF_CRS + 2*DIM + d];
  float k4 = F[OFF_CRS + 3*DIM + d];
  float k5 = F[OFF_CRS + 4*DIM + d];
  float k6 = F[OFF_CRS + 5*DIM + d];
  float k7 = F[OFF_CRS + 6*DIM + d];
  __syncthreads();
  int gw = blockIdx.x * 4 + (t >> 6);
  const int NW = 2048 * 4;
  for (int b = gw; b < BATCH; b += NW) {
    float x = X[(size_t)b*DIM + d];
    bool inside = (x >= -3.f) && (x <= 3.f);
    float xc = fminf(fmaxf(x, -3.f), 3.f);
    int c = (xc>=k1) + (xc>=k2) + (xc>=k3) + (xc>=k4) + (xc>=k5) + (xc>=k6) + (xc>=k7);
    int kb = (c*DIM + d)*4;
    float4 f0 = *(const float4*)&skn[kb];
    float4 f1 = *(const float4*)&skn[2048 + kb];
    int p = c*8 + (xc>=f0.y) + (xc>=f0.z) + (xc>=f0.w)
                + (xc>=f1.x) + (xc>=f1.y) + (xc>=f1.z) + (xc>=f1.w);
    float4 cf = *(const float4*)(F + OFF_CF0 + (size_t)(p*DIM + d)*4);
    float2 cg = *(const float2*)(F + OFF_CF1 + (size_t)(p*DIM + d)*2);
    float xt  = xc - cg.y;
    float num = fmaf(cf.x, xt, cf.y);
    float den = fmaf(cf.z, xt, cf.w);
    float outv = __fdividef(num, den);
    float l2d  = __log2f(fabsf(den));
    float lad2 = fmaf(-2.f, l2d, cg.x);    // log2-units; *ln2 after reduce
    outv = inside ? outv : x;
    lad2 = inside ? lad2 : 0.f;
    OUT[(size_t)b*DIM + d] = outv;
    float ssum = lad2;
    #pragma unroll
    for (int mm = 1; mm < 64; mm <<= 1) ssum += __shfl_xor(ssum, mm, 64);
    if (d == 0) LDo[b] = ssum * 0.69314718055994531f;
  }
}

extern "C" void kernel_launch(void* const* d_in, const int* in_sizes, int n_in,
                              void* d_out, int out_size, void* d_ws, size_t ws_size,
                              hipStream_t stream) {
  const float* x  = (const float*)d_in[0];
  const float* uw = (const float*)d_in[1];
  const float* uh = (const float*)d_in[2];
  const float* ud = (const float*)d_in[3];
  const float* ul = (const float*)d_in[4];
  float* out = (float*)d_out;
  double* W = (double*)d_ws;
  float*  F = (float*)d_ws;
  nf_pre1<<<1, 256, 0, stream>>>(uw, uh, ud, ul, W);
  nf_pre2<<<DIM, 64, 0, stream>>>(W, F);
  nf_pre3<<<DIM, 64, 0, stream>>>(W, F);
  nf_main<<<2048, 256, 0, stream>>>(x, F, out, out + (size_t)BATCH*DIM);
}

// Round 3
// 62.995 us; speedup vs baseline: 1.9696x; 1.9696x over previous
//
#include <hip/hip_runtime.h>

// NormalizingFlow: 4 layers of monotonic linear-rational splines (pyro-style),
// B=262144 rows, D=64 dims, K=8 bins.
//
// Each spline sub-piece (bin x lambda-half) is a Mobius map f(x)=(Ax+B)/(Cx+D);
// Mobius maps compose, so the 4-layer chain per dim is piecewise-Mobius with
// <= 61 pieces. Precompute per-(d,piece) det-normalized (det=1), left-knot-
// recentered matrices; main kernel: 2-level search + one LDS gather + Mobius.
// lad = -2*log2|den| (det==1). Wave-reduce log_det via DPP (lane 63).

#define BATCH 262144
#define DIM   64
#define NLAY  4
#define NK    8

// double-region offsets in d_ws (units: doubles)
#define OFF_LB 0        // [4][64][17] layer input-space piece boundaries
#define OFF_LY 4352     // [4][64][17] layer output-space piece boundaries
#define OFF_LM 8704     // [4][64][16][4] layer piece Mobius matrices (A,B,C,D)
#define OFF_LD 25088    // [4][64][16] log2(det) per layer piece
#define OFF_FB 29184    // [64][65] final composed boundaries (fp64 geometry)
// float-region offsets in d_ws (units: floats from base)
#define OFF_KN0 66688   // [8][64][4] fine knots bnd[8c+0..3] (slot0 = -3.0)
#define OFF_KN1 68736   // [8][64][4] fine knots bnd[8c+4..7]
#define OFF_CRS 70784   // [7][64] coarse knots bnd[8],bnd[16],...,bnd[56]
#define OFF_CF0 71232   // [64][64][4] piece coeffs (A,B',C,D') det-normalized

__device__ __forceinline__ void softmax_knots(const float* p, float minb,
                                              float* kn, float* len) {
  float v[NK];
  float m = p[0];
  for (int k = 1; k < NK; ++k) m = fmaxf(m, p[k]);
  float s = 0.f;
  for (int k = 0; k < NK; ++k) { v[k] = expf(p[k] - m); s += v[k]; }
  float invs = 1.f / s;
  for (int k = 0; k < NK; ++k) v[k] = minb + (1.f - minb * (float)NK) * (v[k] * invs);
  kn[0] = -3.f;
  float c = 0.f;
  for (int k = 0; k < NK; ++k) { c += v[k]; kn[k+1] = 6.f * c - 3.f; }
  kn[NK] = 3.f;
  for (int k = 0; k < NK; ++k) len[k] = kn[k+1] - kn[k];
}

// P1: 256 threads = (layer l, dim d). Replicate reference fp32 param math,
// emit per-layer piece boundaries + Mobius matrices (fp64).
__global__ void nf_pre1(const float* __restrict__ uw, const float* __restrict__ uh,
                        const float* __restrict__ ud, const float* __restrict__ ul,
                        double* __restrict__ W) {
  int t = threadIdx.x;
  int l = t >> 6, d = t & 63;
  const float* pw  = uw + (l*DIM + d)*NK;
  const float* ph  = uh + (l*DIM + d)*NK;
  const float* pdv = ud + (l*DIM + d)*(NK-1);
  const float* pl  = ul + (l*DIM + d)*NK;

  float kw[NK+1], ww[NK], kh[NK+1], hh[NK], dv[NK+1], lm[NK];
  softmax_knots(pw, 1e-3f, kw, ww);
  softmax_knots(ph, 1e-3f, kh, hh);
  dv[0] = 1.f; dv[NK] = 1.f;
  for (int k = 0; k < NK-1; ++k) {
    float u = pdv[k];
    dv[k+1] = 1e-3f + (fmaxf(u, 0.f) + log1pf(expf(-fabsf(u))));
  }
  for (int k = 0; k < NK; ++k) {
    float sg = 1.f / (1.f + expf(-pl[k]));
    lm[k] = 0.95f * sg + 0.025f;
  }

  double* Lb = W + OFF_LB + (l*DIM + d)*17;
  double* Ly = W + OFF_LY + (l*DIM + d)*17;
  double* LM = W + OFF_LM + (l*DIM + d)*64;
  double* Ld = W + OFF_LD + (l*DIM + d)*16;
  Lb[0] = -3.0; Lb[16] = 3.0;
  Ly[0] = -3.0; Ly[16] = 3.0;
  for (int k = 0; k < NK; ++k) {
    float delta = hh[k] / ww[k];
    float wbf = sqrtf(dv[k] / dv[k+1]);
    float wcf = (lm[k]*dv[k] + (1.f-lm[k])*wbf*dv[k+1]) / delta;
    float yaf = kh[k], ybf = hh[k] + kh[k];
    float ycf = ((1.f-lm[k])*yaf + lm[k]*wbf*ybf) / ((1.f-lm[k]) + lm[k]*wbf);
    if (k) Lb[2*k] = (double)(kw[k] + 1.0e-6f);   // bin decision boundary (fp32 +EPS)
    Lb[2*k+1] = (double)kw[k] + (double)lm[k]*(double)ww[k];  // theta==lambda split
    Ly[2*k]   = (double)yaf;
    Ly[2*k+1] = (double)ycf;

    double icw = (double)kw[k], iw = (double)ww[k], il = (double)lm[k];
    double wb = wbf, wc = wcf, ya = yaf, yb = ybf, yc = ycf;
    double n0 = ya*il, n1 = wc*yc - ya, d0 = il, d1 = wc - 1.0;
    double A = n1, Bv = n0*iw - n1*icw, C = d1, Dv = d0*iw - d1*icw;
    double* Mp = LM + (2*k)*4;
    Mp[0]=A; Mp[1]=Bv; Mp[2]=C; Mp[3]=Dv;
    Ld[2*k] = log2(A*Dv - Bv*C);
    n0 = wc*yc - il*wb*yb; n1 = wb*yb - wc*yc; d0 = wc - il*wb; d1 = wb - wc;
    A = n1; Bv = n0*iw - n1*icw; C = d1; Dv = d0*iw - d1*icw;
    Mp = LM + (2*k+1)*4;
    Mp[0]=A; Mp[1]=Bv; Mp[2]=C; Mp[3]=Dv;
    Ld[2*k+1] = log2(A*Dv - Bv*C);
  }
}

// P2: 64 blocks (d) x 64 threads. Pull every layer boundary back to x-space,
// sort by rank, emit fp64 geometry (Fb) + fp32 search tables (kn/crs).
__global__ void nf_pre2(double* __restrict__ W, float* __restrict__ F) {
  int d = blockIdx.x;
  int t = threadIdx.x;
  __shared__ double sx[64];
  if (t < 60) {
    int lp  = t / 15;
    int mth = t % 15 + 1;
    double x = W[OFF_LB + (lp*DIM + d)*17 + mth];
    for (int q = lp - 1; q >= 0; --q) {
      const double* Ly = W + OFF_LY + (q*DIM + d)*17;
      int j = 0;
      for (int k = 1; k <= 15; ++k) j += (x >= Ly[k]) ? 1 : 0;
      const double* M = W + OFF_LM + (q*DIM + d)*64 + j*4;
      x = (M[3]*x - M[1]) / (M[0] - M[2]*x);  // Mobius inverse
    }
    sx[t] = x;
  }
  __syncthreads();
  double* Fb = W + OFF_FB + d*65;
  if (t < 60) {
    double x = sx[t];
    int r = 0;
    for (int s2 = 0; s2 < 60; ++s2) {
      double o = sx[s2];
      r += (o < x || (o == x && s2 < t)) ? 1 : 0;
    }
    Fb[r+1] = x;
  }
  if (t == 0)  Fb[0] = -3.0;
  if (t >= 60) Fb[t+1] = 3.0;
  __threadfence_block();
  __syncthreads();
  int j = t;
  float bf;
  if (j == 0)       bf = -3.0f;         // left edge of piece 0 (recenter anchor)
  else if (j <= 60) bf = (float)Fb[j];
  else              bf = 1e30f;         // search pads: never counted
  int cw = j >> 3, r8 = j & 7;
  if (r8 < 4) F[OFF_KN0 + (cw*DIM + d)*4 + r8]     = bf;
  else        F[OFF_KN1 + (cw*DIM + d)*4 + (r8-4)] = bf;
  if (j >= 8 && (j & 7) == 0 && j <= 56) F[OFF_CRS + (j/8 - 1)*DIM + d] = bf;
}

// P3: 64 blocks (d) x 64 threads (piece p). Compose the 4 layer matrices at the
// piece midpoint; recenter at the piece's LEFT knot (fp32-rounded, matching the
// search table); normalize to det==1 via analytic 2^(-ld2/2); store fp32 coeffs.
__global__ void nf_pre3(const double* __restrict__ W, float* __restrict__ F) {
  int d = blockIdx.x;
  int p = threadIdx.x;
  const double* Fb = W + OFF_FB + d*65;
  double bl = Fb[p], br = Fb[p+1];
  float xmf = (float)(0.5*(bl+br));
  xmf = fminf(fmaxf(xmf, -3.f), 3.f);
  double y = (double)xmf;
  double A=1.0, Bv=0.0, C=0.0, Dv=1.0, ld2 = 0.0;
  for (int q = 0; q < NLAY; ++q) {
    const double* Lb = W + OFF_LB + (q*DIM + d)*17;
    int j = 0;
    for (int k = 1; k <= 15; ++k) j += (y >= Lb[k]) ? 1 : 0;
    const double* M = W + OFF_LM + (q*DIM + d)*64 + j*4;
    ld2 += W[OFF_LD + (q*DIM + d)*16 + j];
    double A2 = M[0]*A + M[1]*C, B2 = M[0]*Bv + M[1]*Dv;
    double C2 = M[2]*A + M[3]*C, D2 = M[2]*Bv + M[3]*Dv;
    y = (M[0]*y + M[1]) / (M[2]*y + M[3]);
    A=A2; Bv=B2; C=C2; Dv=D2;
  }
  float leftf = (p == 0) ? -3.0f : (float)bl;  // matches search-table value
  double xl = (double)leftf;
  double Bp = A*xl + Bv, Dp = C*xl + Dv;       // recenter (unimodular, det kept)
  double sinv = exp2(-0.5 * ld2);              // det of stored matrix -> 1
  float4 c4;
  c4.x = (float)(A*sinv); c4.y = (float)(Bp*sinv);
  c4.z = (float)(C*sinv); c4.w = (float)(Dp*sinv);
  *(float4*)(F + OFF_CF0 + (size_t)(p*DIM + d)*4) = c4;
}

template <int CTRL>
__device__ __forceinline__ float dpp_add(float x) {
  int yi = __builtin_amdgcn_update_dpp(0, __float_as_int(x), CTRL, 0xF, 0xF, false);
  return x + __int_as_float(yi);
}
// wave64 sum -> lane 63 (rocPRIM gfx9 sequence)
__device__ __forceinline__ float wave_sum63(float x) {
  x = dpp_add<0x111>(x);  // row_shr:1
  x = dpp_add<0x112>(x);  // row_shr:2
  x = dpp_add<0x114>(x);  // row_shr:4
  x = dpp_add<0x118>(x);  // row_shr:8
  x = dpp_add<0x142>(x);  // row_bcast:15
  x = dpp_add<0x143>(x);  // row_bcast:31
  return x;
}

// Main: one wave per 2 rows/iter; lane = dim. Knots (16KB) + coeffs (64KB) in
// LDS, conflict-free [g][d][4] layouts. ILP=2 + X prefetch. det==1 Mobius:
// out=(A t + B)/(C t + D), t = xc - left_knot; lad2 = -2 log2|den|.
__global__ __launch_bounds__(1024, 8) void nf_main(const float* __restrict__ X,
                                                   const float* __restrict__ F,
                                                   float* __restrict__ OUT,
                                                   float* __restrict__ LDo) {
  __shared__ float smem[20480];   // [0,4096): knots  [4096,20480): coeffs — 80 KB
  int t = threadIdx.x;
  {
    float4* dst = (float4*)smem;
    const float4* kt = (const float4*)(F + OFF_KN0);
    if (t < 1024) dst[t] = kt[t];
    const float4* ct = (const float4*)(F + OFF_CF0);
    for (int i = t; i < 4096; i += 1024) dst[1024 + i] = ct[i];
  }
  int d = t & 63;
  float k1 = F[OFF_CRS + 0*DIM + d];
  float k2 = F[OFF_CRS + 1*DIM + d];
  float k3 = F[OFF_CRS + 2*DIM + d];
  float k4 = F[OFF_CRS + 3*DIM + d];
  float k5 = F[OFF_CRS + 4*DIM + d];
  float k6 = F[OFF_CRS + 5*DIM + d];
  float k7 = F[OFF_CRS + 6*DIM + d];
  __syncthreads();
  const float4* skv = (const float4*)smem;

  int gw = blockIdx.x * 16 + (t >> 6);          // 0..8191
  const int STRIDE = 8192 * 128;                // floats per iteration step
  const float* Xp = X   + (size_t)gw*128 + d;
  float*       Op = OUT + (size_t)gw*128 + d;
  float x0 = Xp[0], x1 = Xp[64];

#define PROC(xx, oo, ll)                                                      \
  {                                                                           \
    float xc = fminf(fmaxf(xx, -3.f), 3.f);                                   \
    int c = (xc>=k1)+(xc>=k2)+(xc>=k3)+(xc>=k4)+(xc>=k5)+(xc>=k6)+(xc>=k7);   \
    float4 f0 = skv[(c<<6) + d];                                              \
    float4 f1 = skv[512 + (c<<6) + d];                                        \
    bool b1 = xc>=f0.y, b2 = xc>=f0.z, b3 = xc>=f0.w, b4 = xc>=f1.x,          \
         b5 = xc>=f1.y, b6 = xc>=f1.z, b7 = xc>=f1.w;                         \
    int p = (c<<3) + (int)b1+(int)b2+(int)b3+(int)b4+(int)b5+(int)b6+(int)b7; \
    float lf = f0.x;                                                          \
    lf = b1 ? f0.y : lf; lf = b2 ? f0.z : lf; lf = b3 ? f0.w : lf;            \
    lf = b4 ? f1.x : lf; lf = b5 ? f1.y : lf; lf = b6 ? f1.z : lf;            \
    lf = b7 ? f1.w : lf;                                                      \
    float4 cf = skv[1024 + (p<<6) + d];                                       \
    float tt = xc - lf;                                                       \
    float num = fmaf(cf.x, tt, cf.y);                                         \
    float den = fmaf(cf.z, tt, cf.w);                                         \
    bool ins = (xx == xc);                                                    \
    oo = ins ? __fdividef(num, den) : xx;                                     \
    ll = ins ? (-2.f * __log2f(fabsf(den))) : 0.f;                            \
  }

  for (int it = 0; it < 16; ++it) {
    float xn0, xn1;
    if (it < 15) { xn0 = Xp[STRIDE]; xn1 = Xp[STRIDE + 64]; }
    float o0, l0, o1, l1;
    PROC(x0, o0, l0)
    PROC(x1, o1, l1)
    Op[0]  = o0;
    Op[64] = o1;
    float s0 = wave_sum63(l0);
    float s1 = wave_sum63(l1);
    if (d == 63) {
      float2 v; v.x = s0 * 0.69314718055994531f; v.y = s1 * 0.69314718055994531f;
      *(float2*)(LDo + (size_t)it*16384 + 2*gw) = v;
    }
    Xp += STRIDE; Op += STRIDE;
    x0 = xn0; x1 = xn1;
  }
#undef PROC
}

extern "C" void kernel_launch(void* const* d_in, const int* in_sizes, int n_in,
                              void* d_out, int out_size, void* d_ws, size_t ws_size,
                              hipStream_t stream) {
  const float* x  = (const float*)d_in[0];
  const float* uw = (const float*)d_in[1];
  const float* uh = (const float*)d_in[2];
  const float* ud = (const float*)d_in[3];
  const float* ul = (const float*)d_in[4];
  float* out = (float*)d_out;
  double* W = (double*)d_ws;
  float*  F = (float*)d_ws;
  nf_pre1<<<1, 256, 0, stream>>>(uw, uh, ud, ul, W);
  nf_pre2<<<DIM, 64, 0, stream>>>(W, F);
  nf_pre3<<<DIM, 64, 0, stream>>>(W, F);
  nf_main<<<512, 1024, 0, stream>>>(x, F, out, out + (size_t)BATCH*DIM);
}

// Round 4
// 55.312 us; speedup vs baseline: 2.2432x; 1.1389x over previous
//
#include <hip/hip_runtime.h>

// NormalizingFlow: 4 layers of monotonic linear-rational splines (pyro-style),
// B=262144 rows, D=64 dims, K=8 bins.
//
// Each spline sub-piece (bin x lambda-half) is a Mobius map f(x)=(Ax+B)/(Cx+D);
// Mobius maps compose, so the 4-layer chain per dim is piecewise-Mobius with
// <= 61 pieces. One fused precompute kernel (64 blocks = dims, fp64 in LDS)
// builds per-(d,piece) det-normalized (det=1), left-knot-recentered matrices;
// main kernel: 2-level search + one LDS gather + Mobius.
// lad = -2*ln|den| (det==1). Wave-reduce log_det via DPP (lane 63).

#define BATCH 262144
#define DIM   64
#define NLAY  4
#define NK    8

// float offsets in d_ws (units: floats from base)
#define OFF_KN0 0       // [8][64][4] fine knots bnd[8c+0..3] (slot0 = -3.0)
#define OFF_KN1 2048    // [8][64][4] fine knots bnd[8c+4..7]
#define OFF_CRS 4096    // [7][64] coarse knots bnd[8],bnd[16],...,bnd[56]
#define OFF_CF0 4544    // [64][64][4] piece coeffs (A,B',C,D') det-normalized

__device__ __forceinline__ void softmax_knots(const float* p, float minb,
                                              float* kn, float* len) {
  float v[NK];
  float m = p[0];
  for (int k = 1; k < NK; ++k) m = fmaxf(m, p[k]);
  float s = 0.f;
  for (int k = 0; k < NK; ++k) { v[k] = expf(p[k] - m); s += v[k]; }
  float invs = 1.f / s;
  for (int k = 0; k < NK; ++k) v[k] = minb + (1.f - minb * (float)NK) * (v[k] * invs);
  kn[0] = -3.f;
  float c = 0.f;
  for (int k = 0; k < NK; ++k) { c += v[k]; kn[k+1] = 6.f * c - 3.f; }
  kn[NK] = 3.f;
  for (int k = 0; k < NK; ++k) len[k] = kn[k+1] - kn[k];
}

// Fused precompute: one block per dim d (64 blocks x 64 threads).
// Phase 1 (threads 0..3 = layer): fp32 param math -> per-layer piece
//   boundaries + fp64 Mobius matrices, all in LDS.
// Phase 2 (threads 0..59): invert boundaries to x-space, rank-sort -> Fb.
// Phase 3 (thread p): compose 4 matrices at piece midpoint, recenter at left
//   knot (fp32-rounded), normalize det -> 1, emit fp32 tables to F.
__global__ void nf_pre(const float* __restrict__ uw, const float* __restrict__ uh,
                       const float* __restrict__ ud, const float* __restrict__ ul,
                       float* __restrict__ F) {
  __shared__ double Lb[NLAY][17], Ly[NLAY][17], LM[NLAY][16][4], Ld[NLAY][16];
  __shared__ double sx[64], Fb[65];
  int d = blockIdx.x;
  int t = threadIdx.x;

  if (t < NLAY) {
    int l = t;
    const float* pw  = uw + (l*DIM + d)*NK;
    const float* ph  = uh + (l*DIM + d)*NK;
    const float* pdv = ud + (l*DIM + d)*(NK-1);
    const float* pl  = ul + (l*DIM + d)*NK;
    float kw[NK+1], ww[NK], kh[NK+1], hh[NK], dv[NK+1], lm[NK];
    softmax_knots(pw, 1e-3f, kw, ww);
    softmax_knots(ph, 1e-3f, kh, hh);
    dv[0] = 1.f; dv[NK] = 1.f;
    for (int k = 0; k < NK-1; ++k) {
      float u = pdv[k];
      dv[k+1] = 1e-3f + (fmaxf(u, 0.f) + log1pf(expf(-fabsf(u))));
    }
    for (int k = 0; k < NK; ++k) {
      float sg = 1.f / (1.f + expf(-pl[k]));
      lm[k] = 0.95f * sg + 0.025f;
    }
    Lb[l][0] = -3.0; Lb[l][16] = 3.0;
    Ly[l][0] = -3.0; Ly[l][16] = 3.0;
    for (int k = 0; k < NK; ++k) {
      float delta = hh[k] / ww[k];
      float wbf = sqrtf(dv[k] / dv[k+1]);
      float wcf = (lm[k]*dv[k] + (1.f-lm[k])*wbf*dv[k+1]) / delta;
      float yaf = kh[k], ybf = hh[k] + kh[k];
      float ycf = ((1.f-lm[k])*yaf + lm[k]*wbf*ybf) / ((1.f-lm[k]) + lm[k]*wbf);
      if (k) Lb[l][2*k] = (double)(kw[k] + 1.0e-6f);   // bin boundary (fp32 +EPS)
      Lb[l][2*k+1] = (double)kw[k] + (double)lm[k]*(double)ww[k];  // theta==lambda
      Ly[l][2*k]   = (double)yaf;
      Ly[l][2*k+1] = (double)ycf;
      double icw = (double)kw[k], iw = (double)ww[k], il = (double)lm[k];
      double wb = wbf, wc = wcf, ya = yaf, yb = ybf, yc = ycf;
      double n0 = ya*il, n1 = wc*yc - ya, d0 = il, d1 = wc - 1.0;
      double A = n1, Bv = n0*iw - n1*icw, C = d1, Dv = d0*iw - d1*icw;
      LM[l][2*k][0]=A; LM[l][2*k][1]=Bv; LM[l][2*k][2]=C; LM[l][2*k][3]=Dv;
      Ld[l][2*k] = log2(A*Dv - Bv*C);
      n0 = wc*yc - il*wb*yb; n1 = wb*yb - wc*yc; d0 = wc - il*wb; d1 = wb - wc;
      A = n1; Bv = n0*iw - n1*icw; C = d1; Dv = d0*iw - d1*icw;
      LM[l][2*k+1][0]=A; LM[l][2*k+1][1]=Bv; LM[l][2*k+1][2]=C; LM[l][2*k+1][3]=Dv;
      Ld[l][2*k+1] = log2(A*Dv - Bv*C);
    }
  }
  __syncthreads();

  if (t < 60) {
    int lp  = t / 15;
    int mth = t % 15 + 1;
    double x = Lb[lp][mth];
    for (int q = lp - 1; q >= 0; --q) {
      int j = 0;
      for (int k = 1; k <= 15; ++k) j += (x >= Ly[q][k]) ? 1 : 0;
      const double* M = LM[q][j];
      x = (M[3]*x - M[1]) / (M[0] - M[2]*x);  // Mobius inverse
    }
    sx[t] = x;
  }
  __syncthreads();
  if (t < 60) {
    double x = sx[t];
    int r = 0;
    for (int s2 = 0; s2 < 60; ++s2) {
      double o = sx[s2];
      r += (o < x || (o == x && s2 < t)) ? 1 : 0;
    }
    Fb[r+1] = x;
  }
  if (t == 0)  Fb[0] = -3.0;
  if (t >= 60) Fb[t+1] = 3.0;   // Fb[61..64] geometry pads
  __syncthreads();

  // fp32 search tables
  {
    int j = t;
    float bf;
    if (j == 0)       bf = -3.0f;         // left edge of piece 0
    else if (j <= 60) bf = (float)Fb[j];
    else              bf = 1e30f;         // pads: never counted
    int cw = j >> 3, r8 = j & 7;
    if (r8 < 4) F[OFF_KN0 + (cw*DIM + d)*4 + r8]     = bf;
    else        F[OFF_KN1 + (cw*DIM + d)*4 + (r8-4)] = bf;
    if (j >= 8 && (j & 7) == 0 && j <= 56) F[OFF_CRS + (j/8 - 1)*DIM + d] = bf;
  }

  // phase 3: per-piece composed coefficients
  {
    int p = t;
    double bl = Fb[p], br = Fb[p+1];
    float xmf = (float)(0.5*(bl+br));
    xmf = fminf(fmaxf(xmf, -3.f), 3.f);
    double y = (double)xmf;
    double A=1.0, Bv=0.0, C=0.0, Dv=1.0, ld2 = 0.0;
    for (int q = 0; q < NLAY; ++q) {
      int j = 0;
      for (int k = 1; k <= 15; ++k) j += (y >= Lb[q][k]) ? 1 : 0;
      const double* M = LM[q][j];
      ld2 += Ld[q][j];
      double A2 = M[0]*A + M[1]*C, B2 = M[0]*Bv + M[1]*Dv;
      double C2 = M[2]*A + M[3]*C, D2 = M[2]*Bv + M[3]*Dv;
      y = (M[0]*y + M[1]) / (M[2]*y + M[3]);
      A=A2; Bv=B2; C=C2; Dv=D2;
    }
    float leftf = (p == 0) ? -3.0f : (float)bl;  // matches search-table value
    double xl = (double)leftf;
    double Bp = A*xl + Bv, Dp = C*xl + Dv;       // recenter (unimodular)
    double sinv = exp2(-0.5 * ld2);              // det -> 1
    float4 c4;
    c4.x = (float)(A*sinv); c4.y = (float)(Bp*sinv);
    c4.z = (float)(C*sinv); c4.w = (float)(Dp*sinv);
    *(float4*)(F + OFF_CF0 + (size_t)(p*DIM + d)*4) = c4;
  }
}

template <int CTRL>
__device__ __forceinline__ float dpp_add(float x) {
  int yi = __builtin_amdgcn_update_dpp(0, __float_as_int(x), CTRL, 0xF, 0xF, false);
  return x + __int_as_float(yi);
}
// wave64 sum -> lane 63 (rocPRIM gfx9 sequence)
__device__ __forceinline__ float wave_sum63(float x) {
  x = dpp_add<0x111>(x);  // row_shr:1
  x = dpp_add<0x112>(x);  // row_shr:2
  x = dpp_add<0x114>(x);  // row_shr:4
  x = dpp_add<0x118>(x);  // row_shr:8
  x = dpp_add<0x142>(x);  // row_bcast:15
  x = dpp_add<0x143>(x);  // row_bcast:31
  return x;
}

// Main: lane = dim; each wave owns 32 consecutive rows, ILP=4 rows/iter with
// next-iter X prefetch. Knots (16KB) + coeffs (64KB) in LDS, conflict-free
// [g][d][4] layouts. det==1 Mobius: out=(A t + B)/(C t + D), t = xc - left;
// lad = -2 ln|den| (outside-clamp gives lad ~ 0 automatically since f'(+-3)=1).
__global__ __launch_bounds__(1024, 4) void nf_main(const float* __restrict__ X,
                                                   const float* __restrict__ F,
                                                   float* __restrict__ OUT,
                                                   float* __restrict__ LDo) {
  __shared__ float smem[20480];   // [0,4096): knots  [4096,20480): coeffs — 80 KB
  int t = threadIdx.x;
  {
    float4* dst = (float4*)smem;
    const float4* kt = (const float4*)(F + OFF_KN0);
    dst[t] = kt[t];
    const float4* ct = (const float4*)(F + OFF_CF0);
    for (int i = t; i < 4096; i += 1024) dst[1024 + i] = ct[i];
  }
  int d = t & 63;
  float k1 = F[OFF_CRS + 0*DIM + d];
  float k2 = F[OFF_CRS + 1*DIM + d];
  float k3 = F[OFF_CRS + 2*DIM + d];
  float k4 = F[OFF_CRS + 3*DIM + d];
  float k5 = F[OFF_CRS + 4*DIM + d];
  float k6 = F[OFF_CRS + 5*DIM + d];
  float k7 = F[OFF_CRS + 6*DIM + d];
  __syncthreads();
  const float4* skv = (const float4*)smem;

  int gw = blockIdx.x * 16 + (t >> 6);          // 0..8191; wave owns 32 rows
  const float* Xp = X   + (size_t)gw*32*DIM + d;
  float*       Op = OUT + (size_t)gw*32*DIM + d;
  float* Lp = LDo + (size_t)gw*32;

#define PROC(xx, oo, ll)                                                      \
  {                                                                           \
    float xc = fminf(fmaxf(xx, -3.f), 3.f);                                   \
    int c = (xc>=k1)+(xc>=k2)+(xc>=k3)+(xc>=k4)+(xc>=k5)+(xc>=k6)+(xc>=k7);   \
    float4 f0 = skv[(c<<6) + d];                                              \
    float4 f1 = skv[512 + (c<<6) + d];                                        \
    bool b1 = xc>=f0.y, b2 = xc>=f0.z, b3 = xc>=f0.w, b4 = xc>=f1.x,          \
         b5 = xc>=f1.y, b6 = xc>=f1.z, b7 = xc>=f1.w;                         \
    int p = (c<<3) + (int)b1+(int)b2+(int)b3+(int)b4+(int)b5+(int)b6+(int)b7; \
    float lf = f0.x;                                                          \
    lf = b1 ? f0.y : lf; lf = b2 ? f0.z : lf; lf = b3 ? f0.w : lf;            \
    lf = b4 ? f1.x : lf; lf = b5 ? f1.y : lf; lf = b6 ? f1.z : lf;            \
    lf = b7 ? f1.w : lf;                                                      \
    float4 cf = skv[1024 + (p<<6) + d];                                       \
    float tt = xc - lf;                                                       \
    float num = fmaf(cf.x, tt, cf.y);                                         \
    float den = fmaf(cf.z, tt, cf.w);                                         \
    oo = (xx == xc) ? __fdividef(num, den) : xx;                              \
    ll = -1.3862943611198906f * __log2f(fabsf(den));                          \
  }

  float xa0 = Xp[0], xa1 = Xp[64], xa2 = Xp[128], xa3 = Xp[192];
  for (int it = 0; it < 8; ++it) {
    float xb0, xb1, xb2, xb3;
    if (it < 7) {
      xb0 = Xp[256]; xb1 = Xp[320]; xb2 = Xp[384]; xb3 = Xp[448];
    }
    float o0, l0, o1, l1, o2, l2, o3, l3;
    PROC(xa0, o0, l0)
    PROC(xa1, o1, l1)
    PROC(xa2, o2, l2)
    PROC(xa3, o3, l3)
    Op[0] = o0; Op[64] = o1; Op[128] = o2; Op[192] = o3;
    float s0 = wave_sum63(l0);
    float s1 = wave_sum63(l1);
    float s2 = wave_sum63(l2);
    float s3 = wave_sum63(l3);
    if (d == 63) {
      float4 v; v.x = s0; v.y = s1; v.z = s2; v.w = s3;
      *(float4*)Lp = v;
    }
    Xp += 256; Op += 256; Lp += 4;
    xa0 = xb0; xa1 = xb1; xa2 = xb2; xa3 = xb3;
  }
#undef PROC
}

extern "C" void kernel_launch(void* const* d_in, const int* in_sizes, int n_in,
                              void* d_out, int out_size, void* d_ws, size_t ws_size,
                              hipStream_t stream) {
  const float* x  = (const float*)d_in[0];
  const float* uw = (const float*)d_in[1];
  const float* uh = (const float*)d_in[2];
  const float* ud = (const float*)d_in[3];
  const float* ul = (const float*)d_in[4];
  float* out = (float*)d_out;
  float* F = (float*)d_ws;
  nf_pre<<<DIM, 64, 0, stream>>>(uw, uh, ud, ul, F);
  nf_main<<<512, 1024, 0, stream>>>(x, F, out, out + (size_t)BATCH*DIM);
}

// Round 5
// 54.897 us; speedup vs baseline: 2.2601x; 1.0076x over previous
//
#include <hip/hip_runtime.h>

// NormalizingFlow: 4 layers of monotonic linear-rational splines (pyro-style),
// B=262144 rows, D=64 dims, K=8 bins.
//
// Each spline sub-piece (bin x lambda-half) is a Mobius map f(x)=(Ax+B)/(Cx+D);
// Mobius maps compose, so the 4-layer chain per dim is piecewise-Mobius with
// <= 61 pieces. One fused precompute kernel (64 blocks = dims, fp64 in LDS)
// builds per-(d,piece) det-normalized (det=1), left-knot-recentered matrices;
// main kernel: 2-level search + one LDS gather + Mobius.
// lad = -2*ln|den| (det==1). Wave-reduce log_det via DPP (lane 63).
// LDS sized 77KB (61 piece rows) so 2 blocks/CU fit -> 32 waves/CU.

#define BATCH 262144
#define DIM   64
#define NLAY  4
#define NK    8

// float offsets in d_ws (units: floats from base)
#define OFF_KN0 0       // [8][64][4] fine knots bnd[8c+0..3] (slot0 = -3.0)
#define OFF_KN1 2048    // [8][64][4] fine knots bnd[8c+4..7]
#define OFF_CRS 4096    // [7][64] coarse knots bnd[8],bnd[16],...,bnd[56]
#define OFF_CF0 4544    // [64][64][4] piece coeffs (A,B',C,D') det-normalized

__device__ __forceinline__ void softmax_knots(const float* p, float minb,
                                              float* kn, float* len) {
  float v[NK];
  float m = p[0];
  for (int k = 1; k < NK; ++k) m = fmaxf(m, p[k]);
  float s = 0.f;
  for (int k = 0; k < NK; ++k) { v[k] = expf(p[k] - m); s += v[k]; }
  float invs = 1.f / s;
  for (int k = 0; k < NK; ++k) v[k] = minb + (1.f - minb * (float)NK) * (v[k] * invs);
  kn[0] = -3.f;
  float c = 0.f;
  for (int k = 0; k < NK; ++k) { c += v[k]; kn[k+1] = 6.f * c - 3.f; }
  kn[NK] = 3.f;
  for (int k = 0; k < NK; ++k) len[k] = kn[k+1] - kn[k];
}

// Fused precompute: one block per dim d (64 blocks x 64 threads).
__global__ void nf_pre(const float* __restrict__ uw, const float* __restrict__ uh,
                       const float* __restrict__ ud, const float* __restrict__ ul,
                       float* __restrict__ F) {
  __shared__ double Lb[NLAY][17], Ly[NLAY][17], LM[NLAY][16][4], Ld[NLAY][16];
  __shared__ double sx[64], Fb[65];
  int d = blockIdx.x;
  int t = threadIdx.x;

  if (t < NLAY) {
    int l = t;
    const float* pw  = uw + (l*DIM + d)*NK;
    const float* ph  = uh + (l*DIM + d)*NK;
    const float* pdv = ud + (l*DIM + d)*(NK-1);
    const float* pl  = ul + (l*DIM + d)*NK;
    float kw[NK+1], ww[NK], kh[NK+1], hh[NK], dv[NK+1], lm[NK];
    softmax_knots(pw, 1e-3f, kw, ww);
    softmax_knots(ph, 1e-3f, kh, hh);
    dv[0] = 1.f; dv[NK] = 1.f;
    for (int k = 0; k < NK-1; ++k) {
      float u = pdv[k];
      dv[k+1] = 1e-3f + (fmaxf(u, 0.f) + log1pf(expf(-fabsf(u))));
    }
    for (int k = 0; k < NK; ++k) {
      float sg = 1.f / (1.f + expf(-pl[k]));
      lm[k] = 0.95f * sg + 0.025f;
    }
    Lb[l][0] = -3.0; Lb[l][16] = 3.0;
    Ly[l][0] = -3.0; Ly[l][16] = 3.0;
    for (int k = 0; k < NK; ++k) {
      float delta = hh[k] / ww[k];
      float wbf = sqrtf(dv[k] / dv[k+1]);
      float wcf = (lm[k]*dv[k] + (1.f-lm[k])*wbf*dv[k+1]) / delta;
      float yaf = kh[k], ybf = hh[k] + kh[k];
      float ycf = ((1.f-lm[k])*yaf + lm[k]*wbf*ybf) / ((1.f-lm[k]) + lm[k]*wbf);
      if (k) Lb[l][2*k] = (double)(kw[k] + 1.0e-6f);   // bin boundary (fp32 +EPS)
      Lb[l][2*k+1] = (double)kw[k] + (double)lm[k]*(double)ww[k];  // theta==lambda
      Ly[l][2*k]   = (double)yaf;
      Ly[l][2*k+1] = (double)ycf;
      double icw = (double)kw[k], iw = (double)ww[k], il = (double)lm[k];
      double wb = wbf, wc = wcf, ya = yaf, yb = ybf, yc = ycf;
      double n0 = ya*il, n1 = wc*yc - ya, d0 = il, d1 = wc - 1.0;
      double A = n1, Bv = n0*iw - n1*icw, C = d1, Dv = d0*iw - d1*icw;
      LM[l][2*k][0]=A; LM[l][2*k][1]=Bv; LM[l][2*k][2]=C; LM[l][2*k][3]=Dv;
      Ld[l][2*k] = log2(A*Dv - Bv*C);
      n0 = wc*yc - il*wb*yb; n1 = wb*yb - wc*yc; d0 = wc - il*wb; d1 = wb - wc;
      A = n1; Bv = n0*iw - n1*icw; C = d1; Dv = d0*iw - d1*icw;
      LM[l][2*k+1][0]=A; LM[l][2*k+1][1]=Bv; LM[l][2*k+1][2]=C; LM[l][2*k+1][3]=Dv;
      Ld[l][2*k+1] = log2(A*Dv - Bv*C);
    }
  }
  __syncthreads();

  if (t < 60) {
    int lp  = t / 15;
    int mth = t % 15 + 1;
    double x = Lb[lp][mth];
    for (int q = lp - 1; q >= 0; --q) {
      int j = 0;
      for (int k = 1; k <= 15; ++k) j += (x >= Ly[q][k]) ? 1 : 0;
      const double* M = LM[q][j];
      x = (M[3]*x - M[1]) / (M[0] - M[2]*x);  // Mobius inverse
    }
    sx[t] = x;
  }
  __syncthreads();
  if (t < 60) {
    double x = sx[t];
    int r = 0;
    for (int s2 = 0; s2 < 60; ++s2) {
      double o = sx[s2];
      r += (o < x || (o == x && s2 < t)) ? 1 : 0;
    }
    Fb[r+1] = x;
  }
  if (t == 0)  Fb[0] = -3.0;
  if (t >= 60) Fb[t+1] = 3.0;   // Fb[61..64] geometry pads
  __syncthreads();

  // fp32 search tables
  {
    int j = t;
    float bf;
    if (j == 0)       bf = -3.0f;         // left edge of piece 0
    else if (j <= 60) bf = (float)Fb[j];
    else              bf = 1e30f;         // pads: never counted
    int cw = j >> 3, r8 = j & 7;
    if (r8 < 4) F[OFF_KN0 + (cw*DIM + d)*4 + r8]     = bf;
    else        F[OFF_KN1 + (cw*DIM + d)*4 + (r8-4)] = bf;
    if (j >= 8 && (j & 7) == 0 && j <= 56) F[OFF_CRS + (j/8 - 1)*DIM + d] = bf;
  }

  // per-piece composed coefficients
  {
    int p = t;
    double bl = Fb[p], br = Fb[p+1];
    float xmf = (float)(0.5*(bl+br));
    xmf = fminf(fmaxf(xmf, -3.f), 3.f);
    double y = (double)xmf;
    double A=1.0, Bv=0.0, C=0.0, Dv=1.0, ld2 = 0.0;
    for (int q = 0; q < NLAY; ++q) {
      int j = 0;
      for (int k = 1; k <= 15; ++k) j += (y >= Lb[q][k]) ? 1 : 0;
      const double* M = LM[q][j];
      ld2 += Ld[q][j];
      double A2 = M[0]*A + M[1]*C, B2 = M[0]*Bv + M[1]*Dv;
      double C2 = M[2]*A + M[3]*C, D2 = M[2]*Bv + M[3]*Dv;
      y = (M[0]*y + M[1]) / (M[2]*y + M[3]);
      A=A2; Bv=B2; C=C2; Dv=D2;
    }
    float leftf = (p == 0) ? -3.0f : (float)bl;  // matches search-table value
    double xl = (double)leftf;
    double Bp = A*xl + Bv, Dp = C*xl + Dv;       // recenter (unimodular)
    double sinv = exp2(-0.5 * ld2);              // det -> 1
    float4 c4;
    c4.x = (float)(A*sinv); c4.y = (float)(Bp*sinv);
    c4.z = (float)(C*sinv); c4.w = (float)(Dp*sinv);
    *(float4*)(F + OFF_CF0 + (size_t)(p*DIM + d)*4) = c4;
  }
}

template <int CTRL>
__device__ __forceinline__ float dpp_add(float x) {
  int yi = __builtin_amdgcn_update_dpp(0, __float_as_int(x), CTRL, 0xF, 0xF, false);
  return x + __int_as_float(yi);
}
// wave64 sum -> lane 63 (rocPRIM gfx9 sequence)
__device__ __forceinline__ float wave_sum63(float x) {
  x = dpp_add<0x111>(x);  // row_shr:1
  x = dpp_add<0x112>(x);  // row_shr:2
  x = dpp_add<0x114>(x);  // row_shr:4
  x = dpp_add<0x118>(x);  // row_shr:8
  x = dpp_add<0x142>(x);  // row_bcast:15
  x = dpp_add<0x143>(x);  // row_bcast:31
  return x;
}

// Main: lane = dim; each wave owns 32 consecutive rows, stage-separated ILP=2
// with next-iter X prefetch. LDS: knots 16KB + coeffs 61KB = 77KB ->
// 2 blocks/CU (32 waves). det==1 Mobius: out=(A t + B)/(C t + D); lad=-2 ln|den|.
__global__ __launch_bounds__(1024, 8) void nf_main(const float* __restrict__ X,
                                                   const float* __restrict__ F,
                                                   float* __restrict__ OUT,
                                                   float* __restrict__ LDo) {
  __shared__ float smem[19712];   // [0,4096): knots  [4096,19712): 61 coeff rows
  int t = threadIdx.x;
  {
    float4* dst = (float4*)smem;
    const float4* kt = (const float4*)(F + OFF_KN0);
    dst[t] = kt[t];
    const float4* ct = (const float4*)(F + OFF_CF0);
    for (int i = t; i < 3904; i += 1024) dst[1024 + i] = ct[i];
  }
  int d = t & 63;
  float k1 = F[OFF_CRS + 0*DIM + d];
  float k2 = F[OFF_CRS + 1*DIM + d];
  float k3 = F[OFF_CRS + 2*DIM + d];
  float k4 = F[OFF_CRS + 3*DIM + d];
  float k5 = F[OFF_CRS + 4*DIM + d];
  float k6 = F[OFF_CRS + 5*DIM + d];
  float k7 = F[OFF_CRS + 6*DIM + d];
  __syncthreads();
  const float4* skv = (const float4*)smem;

  int gw = blockIdx.x * 16 + (t >> 6);          // 0..8191; wave owns 32 rows
  const float* Xp = X   + (size_t)gw*32*DIM + d;
  float*       Op = OUT + (size_t)gw*32*DIM + d;
  float* Lp = LDo + (size_t)gw*32;

  float xa0 = Xp[0], xa1 = Xp[64];
  for (int it = 0; it < 16; ++it) {
    float xn0, xn1;
    if (it < 15) { xn0 = Xp[128]; xn1 = Xp[192]; }
    // stage 1: clamp + coarse search, both rows
    float xc0 = fminf(fmaxf(xa0, -3.f), 3.f);
    float xc1 = fminf(fmaxf(xa1, -3.f), 3.f);
    int c0 = (xc0>=k1)+(xc0>=k2)+(xc0>=k3)+(xc0>=k4)+(xc0>=k5)+(xc0>=k6)+(xc0>=k7);
    int c1 = (xc1>=k1)+(xc1>=k2)+(xc1>=k3)+(xc1>=k4)+(xc1>=k5)+(xc1>=k6)+(xc1>=k7);
    // stage 2: issue all 4 fine-knot reads
    float4 f00 = skv[(c0<<6) + d];
    float4 f01 = skv[512 + (c0<<6) + d];
    float4 f10 = skv[(c1<<6) + d];
    float4 f11 = skv[512 + (c1<<6) + d];
    // stage 3: fine search, both rows
    bool a1 = xc0>=f00.y, a2 = xc0>=f00.z, a3 = xc0>=f00.w, a4 = xc0>=f01.x,
         a5 = xc0>=f01.y, a6 = xc0>=f01.z, a7 = xc0>=f01.w;
    int p0 = (c0<<3) + (int)a1+(int)a2+(int)a3+(int)a4+(int)a5+(int)a6+(int)a7;
    float lf0 = f00.x;
    lf0 = a1 ? f00.y : lf0; lf0 = a2 ? f00.z : lf0; lf0 = a3 ? f00.w : lf0;
    lf0 = a4 ? f01.x : lf0; lf0 = a5 ? f01.y : lf0; lf0 = a6 ? f01.z : lf0;
    lf0 = a7 ? f01.w : lf0;
    bool b1 = xc1>=f10.y, b2 = xc1>=f10.z, b3 = xc1>=f10.w, b4 = xc1>=f11.x,
         b5 = xc1>=f11.y, b6 = xc1>=f11.z, b7 = xc1>=f11.w;
    int p1 = (c1<<3) + (int)b1+(int)b2+(int)b3+(int)b4+(int)b5+(int)b6+(int)b7;
    float lf1 = f10.x;
    lf1 = b1 ? f10.y : lf1; lf1 = b2 ? f10.z : lf1; lf1 = b3 ? f10.w : lf1;
    lf1 = b4 ? f11.x : lf1; lf1 = b5 ? f11.y : lf1; lf1 = b6 ? f11.z : lf1;
    lf1 = b7 ? f11.w : lf1;
    // stage 4: issue both coeff reads
    float4 cf0 = skv[1024 + (p0<<6) + d];
    float4 cf1 = skv[1024 + (p1<<6) + d];
    // stage 5: math, both rows
    float tt0 = xc0 - lf0;
    float num0 = fmaf(cf0.x, tt0, cf0.y);
    float den0 = fmaf(cf0.z, tt0, cf0.w);
    float o0 = (xa0 == xc0) ? __fdividef(num0, den0) : xa0;
    float l0 = -1.3862943611198906f * __log2f(fabsf(den0));
    float tt1 = xc1 - lf1;
    float num1 = fmaf(cf1.x, tt1, cf1.y);
    float den1 = fmaf(cf1.z, tt1, cf1.w);
    float o1 = (xa1 == xc1) ? __fdividef(num1, den1) : xa1;
    float l1 = -1.3862943611198906f * __log2f(fabsf(den1));
    Op[0] = o0; Op[64] = o1;
    float s0 = wave_sum63(l0);
    float s1 = wave_sum63(l1);
    if (d == 63) {
      float2 v; v.x = s0; v.y = s1;
      *(float2*)Lp = v;
    }
    Xp += 128; Op += 128; Lp += 2;
    xa0 = xn0; xa1 = xn1;
  }
}

extern "C" void kernel_launch(void* const* d_in, const int* in_sizes, int n_in,
                              void* d_out, int out_size, void* d_ws, size_t ws_size,
                              hipStream_t stream) {
  const float* x  = (const float*)d_in[0];
  const float* uw = (const float*)d_in[1];
  const float* uh = (const float*)d_in[2];
  const float* ud = (const float*)d_in[3];
  const float* ul = (const float*)d_in[4];
  float* out = (float*)d_out;
  float* F = (float*)d_ws;
  nf_pre<<<DIM, 64, 0, stream>>>(uw, uh, ud, ul, F);
  nf_main<<<512, 1024, 0, stream>>>(x, F, out, out + (size_t)BATCH*DIM);
}

// Round 6
// 51.778 us; speedup vs baseline: 2.3963x; 1.0602x over previous
//
#include <hip/hip_runtime.h>

// NormalizingFlow: 4 layers of monotonic linear-rational splines (pyro-style),
// B=262144 rows, D=64 dims, K=8 bins.
//
// Each spline sub-piece (bin x lambda-half) is a Mobius map f(x)=(Ax+B)/(Cx+D);
// Mobius maps compose, so the 4-layer chain per dim is piecewise-Mobius with
// <= 61 pieces. Fused precompute builds per-(d,piece) det-normalized (det=1)
// ABSOLUTE coefficient matrices; main kernel: 2-level search + one LDS gather
// + Mobius. lad = -2*ln|den| (det==1). Software-pipelined with
// sched_barrier(0) fences so the LDS reads stay hoisted (defeats the register
// allocator's serialize-to-24-VGPR habit). DPP wave reduce for log_det.

#define BATCH 262144
#define DIM   64
#define NLAY  4
#define NK    8

// float offsets in d_ws (units: floats from base)
#define OFF_KN0 0       // [8][64][4] fine knots bnd[8c+0..3] (slot0 unused)
#define OFF_KN1 2048    // [8][64][4] fine knots bnd[8c+4..7]
#define OFF_CRS 4096    // [7][64] coarse knots bnd[8],bnd[16],...,bnd[56]
#define OFF_CF0 4544    // [61][64][4] piece coeffs (A,B,C,D) det-normalized

__device__ __forceinline__ void softmax_knots(const float* p, float minb,
                                              float* kn, float* len) {
  float v[NK];
  float m = p[0];
  for (int k = 1; k < NK; ++k) m = fmaxf(m, p[k]);
  float s = 0.f;
  for (int k = 0; k < NK; ++k) { v[k] = expf(p[k] - m); s += v[k]; }
  float invs = 1.f / s;
  for (int k = 0; k < NK; ++k) v[k] = minb + (1.f - minb * (float)NK) * (v[k] * invs);
  kn[0] = -3.f;
  float c = 0.f;
  for (int k = 0; k < NK; ++k) { c += v[k]; kn[k+1] = 6.f * c - 3.f; }
  kn[NK] = 3.f;
  for (int k = 0; k < NK; ++k) len[k] = kn[k+1] - kn[k];
}

// Fused precompute: one block per dim d (64 blocks x 64 threads).
__global__ void nf_pre(const float* __restrict__ uw, const float* __restrict__ uh,
                       const float* __restrict__ ud, const float* __restrict__ ul,
                       float* __restrict__ F) {
  __shared__ double Lb[NLAY][17], Ly[NLAY][17], LM[NLAY][16][4], Ld[NLAY][16];
  __shared__ double sx[64], Fb[65];
  int d = blockIdx.x;
  int t = threadIdx.x;

  if (t < NLAY) {
    int l = t;
    const float* pw  = uw + (l*DIM + d)*NK;
    const float* ph  = uh + (l*DIM + d)*NK;
    const float* pdv = ud + (l*DIM + d)*(NK-1);
    const float* pl  = ul + (l*DIM + d)*NK;
    float kw[NK+1], ww[NK], kh[NK+1], hh[NK], dv[NK+1], lm[NK];
    softmax_knots(pw, 1e-3f, kw, ww);
    softmax_knots(ph, 1e-3f, kh, hh);
    dv[0] = 1.f; dv[NK] = 1.f;
    for (int k = 0; k < NK-1; ++k) {
      float u = pdv[k];
      dv[k+1] = 1e-3f + (fmaxf(u, 0.f) + log1pf(expf(-fabsf(u))));
    }
    for (int k = 0; k < NK; ++k) {
      float sg = 1.f / (1.f + expf(-pl[k]));
      lm[k] = 0.95f * sg + 0.025f;
    }
    Lb[l][0] = -3.0; Lb[l][16] = 3.0;
    Ly[l][0] = -3.0; Ly[l][16] = 3.0;
    for (int k = 0; k < NK; ++k) {
      float delta = hh[k] / ww[k];
      float wbf = sqrtf(dv[k] / dv[k+1]);
      float wcf = (lm[k]*dv[k] + (1.f-lm[k])*wbf*dv[k+1]) / delta;
      float yaf = kh[k], ybf = hh[k] + kh[k];
      float ycf = ((1.f-lm[k])*yaf + lm[k]*wbf*ybf) / ((1.f-lm[k]) + lm[k]*wbf);
      if (k) Lb[l][2*k] = (double)(kw[k] + 1.0e-6f);   // bin boundary (fp32 +EPS)
      Lb[l][2*k+1] = (double)kw[k] + (double)lm[k]*(double)ww[k];  // theta==lambda
      Ly[l][2*k]   = (double)yaf;
      Ly[l][2*k+1] = (double)ycf;
      double icw = (double)kw[k], iw = (double)ww[k], il = (double)lm[k];
      double wb = wbf, wc = wcf, ya = yaf, yb = ybf, yc = ycf;
      double n0 = ya*il, n1 = wc*yc - ya, d0 = il, d1 = wc - 1.0;
      double A = n1, Bv = n0*iw - n1*icw, C = d1, Dv = d0*iw - d1*icw;
      LM[l][2*k][0]=A; LM[l][2*k][1]=Bv; LM[l][2*k][2]=C; LM[l][2*k][3]=Dv;
      Ld[l][2*k] = log2(A*Dv - Bv*C);
      n0 = wc*yc - il*wb*yb; n1 = wb*yb - wc*yc; d0 = wc - il*wb; d1 = wb - wc;
      A = n1; Bv = n0*iw - n1*icw; C = d1; Dv = d0*iw - d1*icw;
      LM[l][2*k+1][0]=A; LM[l][2*k+1][1]=Bv; LM[l][2*k+1][2]=C; LM[l][2*k+1][3]=Dv;
      Ld[l][2*k+1] = log2(A*Dv - Bv*C);
    }
  }
  __syncthreads();

  if (t < 60) {
    int lp  = t / 15;
    int mth = t % 15 + 1;
    double x = Lb[lp][mth];
    for (int q = lp - 1; q >= 0; --q) {
      int j = 0;
      for (int k = 1; k <= 15; ++k) j += (x >= Ly[q][k]) ? 1 : 0;
      const double* M = LM[q][j];
      x = (M[3]*x - M[1]) / (M[0] - M[2]*x);  // Mobius inverse
    }
    sx[t] = x;
  }
  __syncthreads();
  if (t < 60) {
    double x = sx[t];
    int r = 0;
    for (int s2 = 0; s2 < 60; ++s2) {
      double o = sx[s2];
      r += (o < x || (o == x && s2 < t)) ? 1 : 0;
    }
    Fb[r+1] = x;
  }
  if (t == 0)  Fb[0] = -3.0;
  if (t >= 60) Fb[t+1] = 3.0;   // Fb[61..64] geometry pads
  __syncthreads();

  // fp32 search tables
  {
    int j = t;
    float bf;
    if (j == 0)       bf = -3.0f;
    else if (j <= 60) bf = (float)Fb[j];
    else              bf = 1e30f;         // pads: never counted
    int cw = j >> 3, r8 = j & 7;
    if (r8 < 4) F[OFF_KN0 + (cw*DIM + d)*4 + r8]     = bf;
    else        F[OFF_KN1 + (cw*DIM + d)*4 + (r8-4)] = bf;
    if (j >= 8 && (j & 7) == 0 && j <= 56) F[OFF_CRS + (j/8 - 1)*DIM + d] = bf;
  }

  // per-piece composed ABSOLUTE coefficients (no recentering), det -> 1
  if (t < 61) {
    int p = t;
    double bl = Fb[p], br = Fb[p+1];
    float xmf = (float)(0.5*(bl+br));
    xmf = fminf(fmaxf(xmf, -3.f), 3.f);
    double y = (double)xmf;
    double A=1.0, Bv=0.0, C=0.0, Dv=1.0, ld2 = 0.0;
    for (int q = 0; q < NLAY; ++q) {
      int j = 0;
      for (int k = 1; k <= 15; ++k) j += (y >= Lb[q][k]) ? 1 : 0;
      const double* M = LM[q][j];
      ld2 += Ld[q][j];
      double A2 = M[0]*A + M[1]*C, B2 = M[0]*Bv + M[1]*Dv;
      double C2 = M[2]*A + M[3]*C, D2 = M[2]*Bv + M[3]*Dv;
      y = (M[0]*y + M[1]) / (M[2]*y + M[3]);
      A=A2; Bv=B2; C=C2; Dv=D2;
    }
    double sinv = exp2(-0.5 * ld2);              // det -> 1
    float4 c4;
    c4.x = (float)(A*sinv); c4.y = (float)(Bv*sinv);
    c4.z = (float)(C*sinv); c4.w = (float)(Dv*sinv);
    *(float4*)(F + OFF_CF0 + (size_t)(p*DIM + d)*4) = c4;
  }
}

template <int CTRL>
__device__ __forceinline__ float dpp_add(float x) {
  int yi = __builtin_amdgcn_update_dpp(0, __float_as_int(x), CTRL, 0xF, 0xF, false);
  return x + __int_as_float(yi);
}
// wave64 sum -> lane 63 (rocPRIM gfx9 sequence)
__device__ __forceinline__ float wave_sum63(float x) {
  x = dpp_add<0x111>(x);  // row_shr:1
  x = dpp_add<0x112>(x);  // row_shr:2
  x = dpp_add<0x114>(x);  // row_shr:4
  x = dpp_add<0x118>(x);  // row_shr:8
  x = dpp_add<0x142>(x);  // row_bcast:15
  x = dpp_add<0x143>(x);  // row_bcast:31
  return x;
}

// Main: lane = dim; each wave owns 32 consecutive rows, processed as 16 units
// of 2 rows, software-pipelined depth 1:
//   R1: coarse(unit k+1) + issue fine-knot reads + prefetch X(unit k+2)
//   R2: math(unit k) with coeffs read LAST iteration (latency fully hidden)
//   R3: fine-search(unit k+1) + issue coeff reads
// sched_barrier(0) between regions pins the schedule (stops load sinking).
__global__ __launch_bounds__(1024, 4) void nf_main(const float* __restrict__ X,
                                                   const float* __restrict__ F,
                                                   float* __restrict__ OUT,
                                                   float* __restrict__ LDo) {
  __shared__ float smem[19712];   // [0,4096): knots  [4096,19712): 61 coeff rows
  int t = threadIdx.x;
  {
    float4* dst = (float4*)smem;
    const float4* kt = (const float4*)(F + OFF_KN0);
    dst[t] = kt[t];
    const float4* ct = (const float4*)(F + OFF_CF0);
    for (int i = t; i < 3904; i += 1024) dst[1024 + i] = ct[i];
  }
  int d = t & 63;
  float k1 = F[OFF_CRS + 0*DIM + d];
  float k2 = F[OFF_CRS + 1*DIM + d];
  float k3 = F[OFF_CRS + 2*DIM + d];
  float k4 = F[OFF_CRS + 3*DIM + d];
  float k5 = F[OFF_CRS + 4*DIM + d];
  float k6 = F[OFF_CRS + 5*DIM + d];
  float k7 = F[OFF_CRS + 6*DIM + d];
  __syncthreads();
  const float4* skv = (const float4*)smem;

  int gw = blockIdx.x * 16 + (t >> 6);          // 0..8191; wave owns 32 rows
  const float* Xb = X   + (size_t)gw*32*DIM + d;
  float*       Ob = OUT + (size_t)gw*32*DIM + d;
  float*       Lp = LDo + (size_t)gw*32;

#define COARSE(xc) ((xc>=k1)+(xc>=k2)+(xc>=k3)+(xc>=k4)+(xc>=k5)+(xc>=k6)+(xc>=k7))
#define FINE(xc, cc, f0, f1) \
  ((cc<<3) + (int)(xc>=f0.y)+(int)(xc>=f0.z)+(int)(xc>=f0.w)+(int)(xc>=f1.x) \
           + (int)(xc>=f1.y)+(int)(xc>=f1.z)+(int)(xc>=f1.w))

  // ---- prologue: full search of unit 0; load x of unit 1 ----
  float xA0 = Xb[0], xA1 = Xb[64];
  float xB0 = Xb[128], xB1 = Xb[192];
  float xcA0 = fminf(fmaxf(xA0, -3.f), 3.f);
  float xcA1 = fminf(fmaxf(xA1, -3.f), 3.f);
  float4 cfA0, cfA1;
  {
    int c0 = COARSE(xcA0), c1 = COARSE(xcA1);
    float4 f00 = skv[(c0<<6)+d], f01 = skv[512+(c0<<6)+d];
    float4 f10 = skv[(c1<<6)+d], f11 = skv[512+(c1<<6)+d];
    int p0 = FINE(xcA0, c0, f00, f01);
    int p1 = FINE(xcA1, c1, f10, f11);
    cfA0 = skv[1024+(p0<<6)+d];
    cfA1 = skv[1024+(p1<<6)+d];
  }

#pragma unroll 3
  for (int it = 0; it < 15; ++it) {
    // ---- R1: coarse(unit it+1), issue fine reads; prefetch x(unit it+2) ----
    float xcB0 = fminf(fmaxf(xB0, -3.f), 3.f);
    float xcB1 = fminf(fmaxf(xB1, -3.f), 3.f);
    int cB0 = COARSE(xcB0), cB1 = COARSE(xcB1);
    float4 f00 = skv[(cB0<<6)+d], f01 = skv[512+(cB0<<6)+d];
    float4 f10 = skv[(cB1<<6)+d], f11 = skv[512+(cB1<<6)+d];
    int u2 = (it < 14) ? (it + 2) : 15;
    float xF0 = Xb[u2*128], xF1 = Xb[u2*128 + 64];
    __builtin_amdgcn_sched_barrier(0);
    // ---- R2: math(unit it) using cfA (read last iteration) ----
    float num0 = fmaf(cfA0.x, xcA0, cfA0.y);
    float den0 = fmaf(cfA0.z, xcA0, cfA0.w);
    float o0 = (xA0 == xcA0) ? __fdividef(num0, den0) : xA0;
    float l0 = -1.3862943611198906f * __log2f(fabsf(den0));
    float num1 = fmaf(cfA1.x, xcA1, cfA1.y);
    float den1 = fmaf(cfA1.z, xcA1, cfA1.w);
    float o1 = (xA1 == xcA1) ? __fdividef(num1, den1) : xA1;
    float l1 = -1.3862943611198906f * __log2f(fabsf(den1));
    Ob[it*128] = o0; Ob[it*128 + 64] = o1;
    float s0 = wave_sum63(l0);
    float s1 = wave_sum63(l1);
    if (d == 63) {
      float2 v; v.x = s0; v.y = s1;
      *(float2*)(Lp + 2*it) = v;
    }
    __builtin_amdgcn_sched_barrier(0);
    // ---- R3: fine-search(unit it+1) + issue coeff reads ----
    int p0 = FINE(xcB0, cB0, f00, f01);
    int p1 = FINE(xcB1, cB1, f10, f11);
    cfA0 = skv[1024+(p0<<6)+d];
    cfA1 = skv[1024+(p1<<6)+d];
    xA0 = xB0; xA1 = xB1; xcA0 = xcB0; xcA1 = xcB1;
    xB0 = xF0; xB1 = xF1;
  }
  // ---- epilogue: math(unit 15) ----
  {
    float num0 = fmaf(cfA0.x, xcA0, cfA0.y);
    float den0 = fmaf(cfA0.z, xcA0, cfA0.w);
    float o0 = (xA0 == xcA0) ? __fdividef(num0, den0) : xA0;
    float l0 = -1.3862943611198906f * __log2f(fabsf(den0));
    float num1 = fmaf(cfA1.x, xcA1, cfA1.y);
    float den1 = fmaf(cfA1.z, xcA1, cfA1.w);
    float o1 = (xA1 == xcA1) ? __fdividef(num1, den1) : xA1;
    float l1 = -1.3862943611198906f * __log2f(fabsf(den1));
    Ob[15*128] = o0; Ob[15*128 + 64] = o1;
    float s0 = wave_sum63(l0);
    float s1 = wave_sum63(l1);
    if (d == 63) {
      float2 v; v.x = s0; v.y = s1;
      *(float2*)(Lp + 30) = v;
    }
  }
#undef COARSE
#undef FINE
}

extern "C" void kernel_launch(void* const* d_in, const int* in_sizes, int n_in,
                              void* d_out, int out_size, void* d_ws, size_t ws_size,
                              hipStream_t stream) {
  const float* x  = (const float*)d_in[0];
  const float* uw = (const float*)d_in[1];
  const float* uh = (const float*)d_in[2];
  const float* ud = (const float*)d_in[3];
  const float* ul = (const float*)d_in[4];
  float* out = (float*)d_out;
  float* F = (float*)d_ws;
  nf_pre<<<DIM, 64, 0, stream>>>(uw, uh, ud, ul, F);
  nf_main<<<512, 1024, 0, stream>>>(x, F, out, out + (size_t)BATCH*DIM);
}